// Round 4
// baseline (465.176 us; speedup 1.0000x reference)
//
#include <hip/hip_runtime.h>
#include <math.h>

#define KDIM   512
#define NCLS   1000
#define CUTOFF 3.0f
#define MAXCAP 4096
#define BN     64          // cols per block (and per wave)
#define NCHUNK (KDIM / 32) // 16 k32-chunks

typedef __attribute__((ext_vector_type(8))) short  short8;
typedef __attribute__((ext_vector_type(4))) float  floatx4;

// ---- ordered-float <-> uint encoding for atomicMax on floats ----
__device__ __forceinline__ unsigned enc_f(float f) {
    unsigned u = __float_as_uint(f);
    return (u & 0x80000000u) ? ~u : (u | 0x80000000u);
}
__device__ __forceinline__ float dec_f(unsigned k) {
    unsigned u = (k & 0x80000000u) ? (k & 0x7FFFFFFFu) : ~k;
    return __uint_as_float(u);
}
// fp32 -> bf16 round-to-nearest-even
__device__ __forceinline__ unsigned short f2bf(float f) {
    unsigned u = __float_as_uint(f);
    u += 0x7FFFu + ((u >> 16) & 1u);
    return (unsigned short)(u >> 16);
}
__device__ __forceinline__ float bf2f(unsigned short h) {
    return __uint_as_float(((unsigned)h) << 16);
}

// Prep: init cnt/gmax; convert A (Brows x 512 fp32) into fragment-major bf16
// hi/lo: af slot (16B units) = ((s16*16 + cg)*2 + h)*64 + lane,
// lane = kq*16 + (r&15), s16 = r>>4, cg = k32-chunk, kq = k-octet in chunk.
__global__ void k_prep(const float* __restrict__ A, unsigned short* __restrict__ af,
                       unsigned* __restrict__ cnt, unsigned* __restrict__ gmax, int Brows) {
    int t = blockIdx.x * blockDim.x + threadIdx.x;
    if (t < Brows) { cnt[t] = 0u; gmax[t] = enc_f(-3.0e38f); }
    if (t >= Brows * (KDIM / 8)) return;
    int r = t >> 6;                 // row (64 k-octets per row)
    int o = t & 63;                 // k-octet index
    int s16 = r >> 4, c = o >> 2, kq = o & 3;
    int lane = kq * 16 + (r & 15);
    const float* src = A + (size_t)r * KDIM + o * 8;
    size_t bhi = ((size_t)((s16 * 16 + c) * 2 + 0) * 64 + lane) * 8;
    size_t blo = ((size_t)((s16 * 16 + c) * 2 + 1) * 64 + lane) * 8;
#pragma unroll
    for (int j = 0; j < 8; ++j) {
        float f = src[j];
        unsigned short h = f2bf(f);
        af[bhi + j] = h;
        af[blo + j] = f2bf(f - bf2f(h));
    }
}

// GEMM: NO LDS, NO barriers. Block = 256 thr = 4 waves; wave w covers rows
// w*64..+64 (rt=4 tiles of 16) x 64 cols (ct=4 tiles of 16). B fragments are
// loaded per-wave directly from global (fp32, fragment layout) and converted
// to bf16 hi/lo in registers; B(cg+1) prefetched one chunk ahead. A fragments
// come from the pre-converted af[] (L2-resident), issued BEFORE the B
// prefetch so their vmcnt wait never drains the in-flight B loads.
__global__ __launch_bounds__(256, 2) void k_gemm(
    const float* __restrict__ Bt,            // [N][512] fp32
    const unsigned short* __restrict__ af,   // A frags bf16 hi/lo
    float* __restrict__ cand_val, int* __restrict__ cand_idx,
    unsigned* __restrict__ cnt, unsigned* __restrict__ gmax,
    int N, int cap)
{
    const int tid  = threadIdx.x;
    const int lane = tid & 63;
    const int wid  = tid >> 6;                 // 0..3 row-group (64 rows each)
    const int colBase = blockIdx.x * BN;
    const int q    = lane >> 4;                // k-octet
    const int n15  = lane & 15;

    // B fragment pointers: per ct, lane reads B[col][cg*32 + q*8 .. +8]
    const float* bp[4];
#pragma unroll
    for (int ct = 0; ct < 4; ++ct) {
        int c = colBase + ct * 16 + n15;
        if (c > N - 1) c = N - 1;              // clamp; masked at epilogue
        bp[ct] = Bt + (size_t)c * KDIM + q * 8;
    }
    // A fragment pointers: shorts index = s16*16384 + cg*1024 + h*512 + lane*8
    const unsigned short* ap[4];
#pragma unroll
    for (int rt = 0; rt < 4; ++rt)
        ap[rt] = af + (size_t)(wid * 4 + rt) * 16384 + lane * 8;

    floatx4 acc[4][4];
#pragma unroll
    for (int rt = 0; rt < 4; ++rt)
#pragma unroll
        for (int ct = 0; ct < 4; ++ct)
            acc[rt][ct] = (floatx4){0.f, 0.f, 0.f, 0.f};

    // prologue: B chunk 0 in flight
    float4 Bf[2][4][2];
#pragma unroll
    for (int ct = 0; ct < 4; ++ct) {
        Bf[0][ct][0] = *(const float4*)(bp[ct]);
        Bf[0][ct][1] = *(const float4*)(bp[ct] + 4);
    }

#pragma unroll 2
    for (int cg = 0; cg < NCHUNK; ++cg) {
        const int cur = cg & 1, nxt = cur ^ 1;

        // 1) A frags for THIS chunk (L2) — issued first
        short8 aH[4], aL[4];
#pragma unroll
        for (int rt = 0; rt < 4; ++rt) {
            const unsigned short* p = ap[rt] + cg * 1024;
            aH[rt] = *(const short8*)(p);
            aL[rt] = *(const short8*)(p + 512);
        }
        // 2) B prefetch for NEXT chunk (HBM) — issued after A
        if (cg < NCHUNK - 1) {
#pragma unroll
            for (int ct = 0; ct < 4; ++ct) {
                const float* p = bp[ct] + (cg + 1) * 32;
                Bf[nxt][ct][0] = *(const float4*)(p);
                Bf[nxt][ct][1] = *(const float4*)(p + 4);
            }
        }
        // 3) convert current B fp32 -> bf16 hi/lo
        short8 bh[4], bl[4];
#pragma unroll
        for (int ct = 0; ct < 4; ++ct) {
            union { float4 v[2]; float f[8]; } P;
            union { short8 v; unsigned short u[8]; } H, L;
            P.v[0] = Bf[cur][ct][0]; P.v[1] = Bf[cur][ct][1];
#pragma unroll
            for (int j = 0; j < 8; ++j) {
                unsigned short h = f2bf(P.f[j]);
                H.u[j] = h; L.u[j] = f2bf(P.f[j] - bf2f(h));
            }
            bh[ct] = H.v; bl[ct] = L.v;
        }
        // 4) 48 MFMAs
#pragma unroll
        for (int ct = 0; ct < 4; ++ct)
#pragma unroll
            for (int rt = 0; rt < 4; ++rt) {
                acc[rt][ct] = __builtin_amdgcn_mfma_f32_16x16x32_bf16(aH[rt], bh[ct], acc[rt][ct], 0, 0, 0);
                acc[rt][ct] = __builtin_amdgcn_mfma_f32_16x16x32_bf16(aH[rt], bl[ct], acc[rt][ct], 0, 0, 0);
                acc[rt][ct] = __builtin_amdgcn_mfma_f32_16x16x32_bf16(aL[rt], bh[ct], acc[rt][ct], 0, 0, 0);
            }
    }

    // ---- epilogue: chunk max, running global max, candidate append ----
    // C/D layout (verified): col = lane&15, row = (lane>>4)*4 + reg
#pragma unroll
    for (int rt = 0; rt < 4; ++rt) {
#pragma unroll
        for (int reg = 0; reg < 4; ++reg) {
            const int row = (wid * 4 + rt) * 16 + q * 4 + reg;
            float m = fmaxf(fmaxf(acc[rt][0][reg], acc[rt][1][reg]),
                            fmaxf(acc[rt][2][reg], acc[rt][3][reg]));
#pragma unroll
            for (int off = 1; off < 16; off <<= 1) m = fmaxf(m, __shfl_xor(m, off));
            unsigned oldk = 0u;
            if (n15 == 0) oldk = atomicMax(&gmax[row], enc_f(m));
            oldk = (unsigned)__shfl((int)oldk, lane & 48);   // quad leader
            const float thr = fmaxf(dec_f(oldk), m) - CUTOFF;
#pragma unroll
            for (int ct = 0; ct < 4; ++ct) {
                const float v = acc[rt][ct][reg];
                const int col = colBase + ct * 16 + n15;
                if (v >= thr && col < N) {
                    unsigned p = atomicAdd(&cnt[row], 1u);
                    if (p < (unsigned)cap) {
                        cand_val[(size_t)row * cap + p] = v;
                        cand_idx[(size_t)row * cap + p] = col;
                    }
                }
            }
        }
    }
}

// One block per row: filter, sort desc, softmax over top-200-equivalent,
// scatter into the 4 k-slices.
__global__ __launch_bounds__(256) void k_finalize(
    const float* __restrict__ cand_val,
    const int* __restrict__ cand_idx,
    const unsigned* __restrict__ cnt,
    const unsigned* __restrict__ gmax,
    const int* __restrict__ labels,
    float* __restrict__ out,
    int Brows, int cap)
{
    __shared__ float s_val[256];
    __shared__ int   s_idx[256];
    __shared__ int   s_n;
    const int row = blockIdx.x;
    const int tid = threadIdx.x;
    if (tid == 0) s_n = 0;
    __syncthreads();

    const float m   = dec_f(gmax[row]);
    const float thr = m - CUTOFF;
    const int n = min((int)cnt[row], cap);
    for (int i = tid; i < n; i += 256) {
        float v = cand_val[(size_t)row * cap + i];
        if (v >= thr) {
            int p = atomicAdd(&s_n, 1);
            if (p < 256) { s_val[p] = v; s_idx[p] = cand_idx[(size_t)row * cap + i]; }
        }
    }
    __syncthreads();

    for (int c = tid; c < 4 * NCLS; c += 256) {
        int s = c / NCLS, cc = c - s * NCLS;
        out[(size_t)s * ((size_t)Brows * NCLS) + (size_t)row * NCLS + cc] = 0.f;
    }
    __syncthreads();

    if (tid == 0) {
        int ns = min(s_n, 256);
        for (int i = 1; i < ns; ++i) {            // tiny insertion sort desc
            float v = s_val[i]; int ix = s_idx[i];
            int j = i - 1;
            while (j >= 0 && s_val[j] < v) { s_val[j+1] = s_val[j]; s_idx[j+1] = s_idx[j]; --j; }
            s_val[j+1] = v; s_idx[j+1] = ix;
        }
        if (ns > 200) ns = 200;
        float Z = 0.f;
        for (int i = 0; i < ns; ++i) Z += expf((s_val[i] - m) / 0.07f);
        float invZ = 1.f / Z;
        const int kv[4] = {10, 20, 100, 200};
        for (int i = 0; i < ns; ++i) {
            float w = expf((s_val[i] - m) / 0.07f) * invZ;
            int lab = labels[s_idx[i]];
#pragma unroll
            for (int s = 0; s < 4; ++s)
                if (i < kv[s])
                    out[(size_t)s * ((size_t)Brows * NCLS) + (size_t)row * NCLS + lab] += w;
        }
    }
}

extern "C" void kernel_launch(void* const* d_in, const int* in_sizes, int n_in,
                              void* d_out, int out_size, void* d_ws, size_t ws_size,
                              hipStream_t stream) {
    const float* A      = (const float*)d_in[0];   // (256, 512)
    const float* Bt     = (const float*)d_in[1];   // (100000, 512)
    const int*   labels = (const int*)d_in[2];     // (100000,)
    float* out = (float*)d_out;                    // (4, 256, 1000)

    const int Brows = in_sizes[0] / KDIM;          // 256
    const int N     = in_sizes[2];                 // 100000

    // ws layout: af (Brows*512*2 bf16 hi+lo) | cnt | gmax | cand_val | cand_idx
    size_t af_elems = (size_t)Brows * KDIM * 2;
    unsigned short* af = (unsigned short*)d_ws;
    unsigned* cnt  = (unsigned*)(af + af_elems);
    unsigned* gmax = cnt + Brows;
    char* rest = (char*)(gmax + Brows);
    size_t used  = (size_t)(rest - (char*)d_ws);
    size_t avail = (ws_size > used) ? (ws_size - used) : 0;
    int cap = (int)((avail / ((size_t)Brows * 8)) < (size_t)MAXCAP
                        ? (avail / ((size_t)Brows * 8)) : (size_t)MAXCAP);
    if (cap < 1) cap = 1;
    float* cand_val = (float*)rest;
    int*   cand_idx = (int*)(cand_val + (size_t)Brows * cap);

    k_prep<<<(Brows * (KDIM / 8) + 255) / 256, 256, 0, stream>>>(A, af, cnt, gmax, Brows);
    k_gemm<<<(N + BN - 1) / BN, 256, 0, stream>>>(Bt, af, cand_val, cand_idx, cnt, gmax, N, cap);
    k_finalize<<<Brows, 256, 0, stream>>>(cand_val, cand_idx, cnt, gmax, labels, out, Brows, cap);
}

// Round 5
// 457.797 us; speedup vs baseline: 1.0161x; 1.0161x over previous
//
#include <hip/hip_runtime.h>
#include <math.h>

#define KDIM   512
#define NCLS   1000
#define CUTOFF 3.7f        // collection cutoff: 3.0 (weight < e^-43) + ~10 sigma bf16-trunc margin
#define MAXCAP 4096
#define BN     64
#define NST    16          // K stages of 32

typedef __attribute__((ext_vector_type(8))) short  short8;
typedef __attribute__((ext_vector_type(4))) float  floatx4;

// ---- ordered-float <-> uint encoding for atomicMax on floats ----
__device__ __forceinline__ unsigned enc_f(float f) {
    unsigned u = __float_as_uint(f);
    return (u & 0x80000000u) ? ~u : (u | 0x80000000u);
}
__device__ __forceinline__ float dec_f(unsigned k) {
    unsigned u = (k & 0x80000000u) ? (k & 0x7FFFFFFFu) : ~k;
    return __uint_as_float(u);
}
// fp32 -> bf16 round-to-nearest-even (used for A prep only)
__device__ __forceinline__ unsigned short f2bf(float f) {
    unsigned u = __float_as_uint(f);
    u += 0x7FFFu + ((u >> 16) & 1u);
    return (unsigned short)(u >> 16);
}

__device__ __forceinline__ void glds16(const float* g, unsigned* l) {
    __builtin_amdgcn_global_load_lds(
        (const __attribute__((address_space(1))) unsigned*)g,
        (__attribute__((address_space(3))) unsigned*)l, 16, 0, 0);
}

// Prep: init cnt/gmax; convert A (Brows x 512 fp32) into fragment-major bf16
// (hi only): af slot (16B) = (s16*16 + cg)*64 + lane, lane = kq*16 + (r&15).
__global__ void k_prep(const float* __restrict__ A, unsigned short* __restrict__ af,
                       unsigned* __restrict__ cnt, unsigned* __restrict__ gmax, int Brows) {
    int t = blockIdx.x * blockDim.x + threadIdx.x;
    if (t < Brows) { cnt[t] = 0u; gmax[t] = enc_f(-3.0e38f); }
    if (t >= Brows * (KDIM / 8)) return;
    int r = t >> 6;                 // row
    int o = t & 63;                 // k-octet
    int s16 = r >> 4, cg = o >> 2, kq = o & 3;
    int lane = kq * 16 + (r & 15);
    const float* src = A + (size_t)r * KDIM + o * 8;
    size_t b = ((size_t)(s16 * 16 + cg) * 64 + lane) * 8;
#pragma unroll
    for (int j = 0; j < 8; ++j) af[b + j] = f2bf(src[j]);
}

// GEMM: single-pass truncated-bf16 (filter-grade sims; exact rescore later).
// Block = 256 thr = 4 waves; wave w: rows w*64..+64 (all 256 rows), BN=64 cols.
// B staged fp32 via global_load_lds (DMA, no VGPR round trip), BK=32,
// double-buffered, ONE barrier/stage. LDS slot f(col,q4)=col*8+(q4^(col&7))
// (swizzle applied on the DMA *source* address since dst must be linear)
// -> frag reads are 2-way-conflict-only b128s. A-frag loads are issued BEFORE
// the next-stage DMA so their vmcnt wait leaves the DMA in flight.
__global__ __launch_bounds__(256, 3) void k_gemm(
    const float* __restrict__ Bt,            // [N][512] fp32
    const unsigned short* __restrict__ af,   // A frags bf16
    float* __restrict__ cand_val, int* __restrict__ cand_idx,
    unsigned* __restrict__ cnt, unsigned* __restrict__ gmax,
    int N, int cap)
{
    __shared__ unsigned Bs[2][2048];          // 2 x 8 KB fp32 B tiles

    const int tid  = threadIdx.x;
    const int lane = tid & 63;
    const int w    = tid >> 6;                // 0..3
    const int q    = lane >> 4;
    const int n15  = lane & 15;
    const int colBase = blockIdx.x * BN;

    // DMA mapping: issue i slot s=i*256+tid -> col=s>>3, q4=(s&7)^(col&7)
    const int s0 = tid, s1 = tid + 256;
    const int c0 = s0 >> 3, c1 = s1 >> 3;
    const int q40 = (s0 & 7) ^ (c0 & 7), q41 = (s1 & 7) ^ (c1 & 7);
    int gc0 = colBase + c0; if (gc0 > N - 1) gc0 = N - 1;
    int gc1 = colBase + c1; if (gc1 > N - 1) gc1 = N - 1;
    const float* g0 = Bt + (size_t)gc0 * KDIM + q40 * 4;
    const float* g1 = Bt + (size_t)gc1 * KDIM + q41 * 4;

    floatx4 acc[4][4];
#pragma unroll
    for (int rt = 0; rt < 4; ++rt)
#pragma unroll
        for (int ct = 0; ct < 4; ++ct)
            acc[rt][ct] = (floatx4){0.f, 0.f, 0.f, 0.f};

    glds16(g0, &Bs[0][s0 * 4]);               // stage 0 in flight
    glds16(g1, &Bs[0][s1 * 4]);

#pragma unroll 2
    for (int ks = 0; ks < NST; ++ks) {
        __syncthreads();                      // DMA(ks) complete; buf^1 free

        short8 aH[4];                         // A loads FIRST (older than DMA)
#pragma unroll
        for (int rt = 0; rt < 4; ++rt)
            aH[rt] = *(const short8*)(af + ((size_t)((w * 4 + rt) * 16 + ks) * 64 + lane) * 8);

        if (ks + 1 < NST) {                   // DMA next stage into other buf
            glds16(g0 + (ks + 1) * 32, &Bs[(ks + 1) & 1][s0 * 4]);
            glds16(g1 + (ks + 1) * 32, &Bs[(ks + 1) & 1][s1 * 4]);
        }

        const unsigned* bs = Bs[ks & 1];
        short8 bh[4];
#pragma unroll
        for (int ct = 0; ct < 4; ++ct) {
            const int col = ct * 16 + n15;
            const int g2 = col & 7, base = col * 8;
            union { float4 f; unsigned u[4]; } A0, A1;
            A0.f = *(const float4*)&bs[(base + ((2 * q) ^ g2)) * 4];
            A1.f = *(const float4*)&bs[(base + ((2 * q + 1) ^ g2)) * 4];
            union { unsigned u[4]; short8 v; } R;   // truncate-pack fp32->bf16
            R.u[0] = (A0.u[1] & 0xFFFF0000u) | (A0.u[0] >> 16);
            R.u[1] = (A0.u[3] & 0xFFFF0000u) | (A0.u[2] >> 16);
            R.u[2] = (A1.u[1] & 0xFFFF0000u) | (A1.u[0] >> 16);
            R.u[3] = (A1.u[3] & 0xFFFF0000u) | (A1.u[2] >> 16);
            bh[ct] = R.v;
        }
#pragma unroll
        for (int ct = 0; ct < 4; ++ct)
#pragma unroll
            for (int rt = 0; rt < 4; ++rt)
                acc[rt][ct] = __builtin_amdgcn_mfma_f32_16x16x32_bf16(aH[rt], bh[ct], acc[rt][ct], 0, 0, 0);
    }

    // ---- epilogue: row max, running global max, candidate append ----
    // C/D layout: col = lane&15, row = (lane>>4)*4 + reg
#pragma unroll
    for (int rt = 0; rt < 4; ++rt) {
#pragma unroll
        for (int reg = 0; reg < 4; ++reg) {
            const int row = (w * 4 + rt) * 16 + q * 4 + reg;
            float m = fmaxf(fmaxf(acc[rt][0][reg], acc[rt][1][reg]),
                            fmaxf(acc[rt][2][reg], acc[rt][3][reg]));
#pragma unroll
            for (int off = 1; off < 16; off <<= 1) m = fmaxf(m, __shfl_xor(m, off));
            unsigned oldk = 0u;
            if (n15 == 0) oldk = atomicMax(&gmax[row], enc_f(m));
            oldk = (unsigned)__shfl((int)oldk, lane & 48);
            const float thr = fmaxf(dec_f(oldk), m) - CUTOFF;
#pragma unroll
            for (int ct = 0; ct < 4; ++ct) {
                const float v = acc[rt][ct][reg];
                const int col = colBase + ct * 16 + n15;
                if (v >= thr && col < N) {
                    unsigned p = atomicAdd(&cnt[row], 1u);
                    if (p < (unsigned)cap) {
                        cand_val[(size_t)row * cap + p] = v;
                        cand_idx[(size_t)row * cap + p] = col;
                    }
                }
            }
        }
    }
}

// One block per row: filter (approx), EXACT fp32 rescore of survivors,
// sort desc, softmax (top-200 semantics), scatter into 4 k-slices.
__global__ __launch_bounds__(256) void k_finalize(
    const float* __restrict__ A,             // (Brows,512) fp32
    const float* __restrict__ Bt,            // (N,512) fp32
    const float* __restrict__ cand_val,
    const int* __restrict__ cand_idx,
    const unsigned* __restrict__ cnt,
    const unsigned* __restrict__ gmax,
    const int* __restrict__ labels,
    float* __restrict__ out,
    int Brows, int cap)
{
    __shared__ float s_val[256];
    __shared__ int   s_idx[256];
    __shared__ float s_arow[KDIM];
    __shared__ int   s_n;
    const int row = blockIdx.x;
    const int tid = threadIdx.x;
    if (tid == 0) s_n = 0;
    for (int i = tid; i < KDIM; i += 256) s_arow[i] = A[(size_t)row * KDIM + i];
    __syncthreads();

    const float ma  = dec_f(gmax[row]);       // approx (bf16-grade) running max
    const float thr = ma - CUTOFF;
    const int n = min((int)cnt[row], cap);
    for (int i = tid; i < n; i += 256) {
        float v = cand_val[(size_t)row * cap + i];
        if (v >= thr) {
            int p = atomicAdd(&s_n, 1);
            if (p < 256) { s_val[p] = v; s_idx[p] = cand_idx[(size_t)row * cap + i]; }
        }
    }
    __syncthreads();

    const int ns = min(s_n, 256);
    // exact rescore: one wave per candidate, lane covers 8 k-elements
    const int wv = tid >> 6, l = tid & 63;
    for (int i = wv; i < ns; i += 4) {
        const float* brow = Bt + (size_t)s_idx[i] * KDIM;
        float p = 0.f;
#pragma unroll
        for (int j = 0; j < 8; ++j) p += s_arow[l * 8 + j] * brow[l * 8 + j];
#pragma unroll
        for (int off = 1; off < 64; off <<= 1) p += __shfl_xor(p, off);
        if (l == 0) s_val[i] = p;             // overwrite approx with exact
    }

    // zero this row's 4 output slices
    for (int c = tid; c < 4 * NCLS; c += 256) {
        int s = c / NCLS, cc = c - s * NCLS;
        out[(size_t)s * ((size_t)Brows * NCLS) + (size_t)row * NCLS + cc] = 0.f;
    }
    __syncthreads();

    if (tid == 0) {
        int m = ns;
        for (int i = 1; i < m; ++i) {         // insertion sort desc (exact vals)
            float v = s_val[i]; int ix = s_idx[i];
            int j = i - 1;
            while (j >= 0 && s_val[j] < v) { s_val[j+1] = s_val[j]; s_idx[j+1] = s_idx[j]; --j; }
            s_val[j+1] = v; s_idx[j+1] = ix;
        }
        if (m > 200) m = 200;                 // reference softmax spans top-200
        const float mx = s_val[0];
        float Z = 0.f;
        for (int i = 0; i < m; ++i) Z += expf((s_val[i] - mx) / 0.07f);
        float invZ = 1.f / Z;
        const int kv[4] = {10, 20, 100, 200};
        for (int i = 0; i < m; ++i) {
            float wgt = expf((s_val[i] - mx) / 0.07f) * invZ;
            int lab = labels[s_idx[i]];
#pragma unroll
            for (int s = 0; s < 4; ++s)
                if (i < kv[s])
                    out[(size_t)s * ((size_t)Brows * NCLS) + (size_t)row * NCLS + lab] += wgt;
        }
    }
}

extern "C" void kernel_launch(void* const* d_in, const int* in_sizes, int n_in,
                              void* d_out, int out_size, void* d_ws, size_t ws_size,
                              hipStream_t stream) {
    const float* A      = (const float*)d_in[0];   // (256, 512)
    const float* Bt     = (const float*)d_in[1];   // (100000, 512)
    const int*   labels = (const int*)d_in[2];     // (100000,)
    float* out = (float*)d_out;                    // (4, 256, 1000)

    const int Brows = in_sizes[0] / KDIM;          // 256
    const int N     = in_sizes[2];                 // 100000

    // ws: af (Brows*512 bf16) | cnt | gmax | cand_val | cand_idx
    size_t af_elems = (size_t)Brows * KDIM;
    unsigned short* af = (unsigned short*)d_ws;
    unsigned* cnt  = (unsigned*)(af + af_elems);
    unsigned* gmax = cnt + Brows;
    char* rest = (char*)(gmax + Brows);
    size_t used  = (size_t)(rest - (char*)d_ws);
    size_t avail = (ws_size > used) ? (ws_size - used) : 0;
    size_t pairs = avail / ((size_t)Brows * 8);
    int cap = (int)(pairs < (size_t)MAXCAP ? pairs : (size_t)MAXCAP);
    if (cap < 1) cap = 1;
    float* cand_val = (float*)rest;
    int*   cand_idx = (int*)(cand_val + (size_t)Brows * cap);

    k_prep<<<(Brows * (KDIM / 8) + 255) / 256, 256, 0, stream>>>(A, af, cnt, gmax, Brows);
    k_gemm<<<(N + BN - 1) / BN, 256, 0, stream>>>(Bt, af, cand_val, cand_idx, cnt, gmax, N, cap);
    k_finalize<<<Brows, 256, 0, stream>>>(A, Bt, cand_val, cand_idx, cnt, gmax, labels, out, Brows, cap);
}